// Round 5
// baseline (125.257 us; speedup 1.0000x reference)
//
#include <hip/hip_runtime.h>

// N = 8192 rows, D = 512 features.
// loss = mean((1-cos)^2) over all pairs (margin=1 makes labels irrelevant:
//        max(1-cos,0)^2 == (1-cos)^2 since cos <= 1).
// N^2*loss = N^2 - 2*||s||^2 + ||Xn^T Xn||_F^2,  s_a = sum_i xn[i][a].
// G = Xn^T Xn is 512x512 symmetric -> 136 upper-triangle 32x32 tiles,
// off-diagonal tiles weighted 2 in the Frobenius sum.

typedef __attribute__((ext_vector_type(8))) short  s8;      // 8 bf16 payload
typedef __attribute__((ext_vector_type(8))) __bf16 bf8;     // mfma operand
typedef __attribute__((ext_vector_type(4))) float  f4;
typedef __attribute__((ext_vector_type(4))) unsigned short u4v;

#define NT32 136                 // 16*17/2 upper-triangle 32x32 tiles
#define KOUT 32                  // K splits (32 chunks of 256)
#define KCW  256                 // 8192 / KOUT
#define PLANE_F4 (NT32 * 256)    // f4 cells per partial plane (34816)
#define RB 1088                  // reduce blocks = 34816 / 32

// ws layout (bytes)
#define OFF_XT  0u                               // bf16 xt[512][8192] = 8 MiB
#define OFF_INV (8u * 1024u * 1024u)             // f32 inv[8192]
#define OFF_S   (OFF_INV + 8192u * 4u)           // f32 svec[512]
#define OFF_S2  (OFF_S + 512u * 4u)              // f32 s2[1]
#define OFF_TK  (OFF_S2 + 4u)                    // int ticket[1]
#define OFF_GP  (OFF_S2 + 64u)                   // f32 gp[KOUT][NT32][1024] = 17.8 MiB

__device__ __forceinline__ unsigned short f2bf(float f) {
    union { float f; unsigned u; } v; v.f = f;
    unsigned r = v.u + 0x7FFFu + ((v.u >> 16) & 1u);   // RNE
    return (unsigned short)(r >> 16);
}

// --- K1a: per-row inv-norms (one wave/row) + zero svec/s2/ticket from blk 0 ---
__global__ __launch_bounds__(256) void k_norms(
    const float* __restrict__ reps, float* __restrict__ inv,
    float* __restrict__ zbuf /* svec[512] + s2 + ticket contiguous */)
{
    const int t = threadIdx.x, lane = t & 63, w = t >> 6;
    if (blockIdx.x == 0) {
        for (int z = t; z < 514; z += 256) zbuf[z] = 0.f;
    }
    const int row = blockIdx.x * 4 + w;
    const float4 x0 = *(const float4*)(reps + (size_t)row * 512 + lane * 4);
    const float4 x1 = *(const float4*)(reps + (size_t)row * 512 + 256 + lane * 4);
    float ss = x0.x*x0.x + x0.y*x0.y + x0.z*x0.z + x0.w*x0.w
             + x1.x*x1.x + x1.y*x1.y + x1.z*x1.z + x1.w*x1.w;
    #pragma unroll
    for (int off = 1; off < 64; off <<= 1) ss += __shfl_xor(ss, off, 64);
    if (lane == 0) inv[row] = 1.0f / fmaxf(sqrtf(ss), 1e-8f);
}

// --- K1b: normalize + bf16 + 64x64 transpose (XOR-swizzled LDS) + s-vector ---
__global__ __launch_bounds__(256) void k_norm_transpose(
    const float* __restrict__ reps, const float* __restrict__ inv,
    unsigned short* __restrict__ xt, float* __restrict__ svec)
{
    __shared__ unsigned short tile[64 * 64];    // swizzled: no pad needed
    __shared__ float sred[4][64];
    const int t = threadIdx.x, lane = t & 63, w = t >> 6;
    const int a0 = blockIdx.x * 64, i0 = blockIdx.y * 64;
    const int colg = t & 15;                    // col group: cols colg*4..+3
    const int ig0  = t >> 4;                    // 0..15

    float4 sa = {0.f, 0.f, 0.f, 0.f};
    #pragma unroll
    for (int j = 0; j < 4; ++j) {
        const int il = ig0 + j * 16;
        const float iv = inv[i0 + il];
        const float4 x = *(const float4*)(reps + (size_t)(i0 + il) * 512 + a0 + colg * 4);
        const float4 xn = {x.x * iv, x.y * iv, x.z * iv, x.w * iv};
        sa.x += xn.x; sa.y += xn.y; sa.z += xn.z; sa.w += xn.w;
        ushort4 p;
        p.x = f2bf(xn.x); p.y = f2bf(xn.y); p.z = f2bf(xn.z); p.w = f2bf(xn.w);
        // column XOR-swizzle by (row>>2)&7 -> conflict-free phase-2 reads
        *(ushort4*)&tile[il * 64 + ((colg * 4) ^ (((il >> 2) & 7) << 3))] = p;
    }
    __syncthreads();

    // phase 2: register 4x4 sub-block transpose -> coalesced xt writes
    {
        const int ig = t & 15, ag = t >> 4;
        u4v rows[4];
        #pragma unroll
        for (int r = 0; r < 4; ++r)
            rows[r] = *(const u4v*)&tile[(ig * 4 + r) * 64 + ((ag * 4) ^ ((ig & 7) << 3))];
        #pragma unroll
        for (int j = 0; j < 4; ++j) {
            ushort4 o;
            o.x = (unsigned short)rows[0][j];
            o.y = (unsigned short)rows[1][j];
            o.z = (unsigned short)rows[2][j];
            o.w = (unsigned short)rows[3][j];
            *(ushort4*)(xt + (size_t)(a0 + ag * 4 + j) * 8192 + i0 + ig * 4) = o;
        }
    }

    // s-vector: reduce over 16 i-groups (in-wave via shfl, cross-wave via LDS)
    sa.x += __shfl_xor(sa.x, 16, 64); sa.x += __shfl_xor(sa.x, 32, 64);
    sa.y += __shfl_xor(sa.y, 16, 64); sa.y += __shfl_xor(sa.y, 32, 64);
    sa.z += __shfl_xor(sa.z, 16, 64); sa.z += __shfl_xor(sa.z, 32, 64);
    sa.w += __shfl_xor(sa.w, 16, 64); sa.w += __shfl_xor(sa.w, 32, 64);
    if (lane < 16) {
        sred[w][lane * 4 + 0] = sa.x; sred[w][lane * 4 + 1] = sa.y;
        sred[w][lane * 4 + 2] = sa.z; sred[w][lane * 4 + 3] = sa.w;
    }
    __syncthreads();
    if (t < 64) {
        const float v = sred[0][t] + sred[1][t] + sred[2][t] + sred[3][t];
        atomicAdd(&svec[a0 + t], v);
    }
}

// --- K2: partial Gram, 32x32 upper-tri tiles; 1 wave = 1 tile x K-chunk.
//     XCD-pinned: all 32 K-chunks of a tile land on one XCD (L2 locality). ---
__global__ __launch_bounds__(64, 4) void k_gram(
    const unsigned short* __restrict__ xt, float* __restrict__ gp)
{
    const int lane = threadIdx.x;
    const int l15 = lane & 15, l4 = lane >> 4;
    const int lin = blockIdx.x;                  // 4352 blocks, rr over 8 XCDs
    const int xcd = lin & 7, j = lin >> 3;       // j in [0,544)
    const int tIdx = xcd * 17 + (j >> 5);        // tile 0..135, pinned per XCD
    const int kc   = j & 31;                     // K-chunk 0..31
    int tt = tIdx, ta = 0;
    while (tt >= 16 - ta) { tt -= 16 - ta; ++ta; }
    const int tb = ta + tt;
    const unsigned short* A0 = xt + (size_t)(ta * 32 + l15) * 8192 + kc * KCW + l4 * 8;
    const unsigned short* B0 = xt + (size_t)(tb * 32 + l15) * 8192 + kc * KCW + l4 * 8;

    f4 acc00 = {0.f,0.f,0.f,0.f}, acc01 = {0.f,0.f,0.f,0.f};
    f4 acc10 = {0.f,0.f,0.f,0.f}, acc11 = {0.f,0.f,0.f,0.f};

    #pragma unroll 4
    for (int k = 0; k < KCW; k += 32) {
        const s8 av0 = *(const s8*)(A0 + k);
        const s8 av1 = *(const s8*)(A0 + 16 * 8192 + k);
        const s8 bv0 = *(const s8*)(B0 + k);
        const s8 bv1 = *(const s8*)(B0 + 16 * 8192 + k);
        acc00 = __builtin_amdgcn_mfma_f32_16x16x32_bf16(
            __builtin_bit_cast(bf8, av0), __builtin_bit_cast(bf8, bv0), acc00, 0, 0, 0);
        acc01 = __builtin_amdgcn_mfma_f32_16x16x32_bf16(
            __builtin_bit_cast(bf8, av0), __builtin_bit_cast(bf8, bv1), acc01, 0, 0, 0);
        acc10 = __builtin_amdgcn_mfma_f32_16x16x32_bf16(
            __builtin_bit_cast(bf8, av1), __builtin_bit_cast(bf8, bv0), acc10, 0, 0, 0);
        acc11 = __builtin_amdgcn_mfma_f32_16x16x32_bf16(
            __builtin_bit_cast(bf8, av1), __builtin_bit_cast(bf8, bv1), acc11, 0, 0, 0);
    }

    float* gb = gp + ((size_t)kc * NT32 + tIdx) * 1024;
    #pragma unroll
    for (int r = 0; r < 4; ++r) {
        const int ar0 = (l4 * 4 + r) * 32 + l15;         // C/D: row=(l>>4)*4+r, col=l&15
        gb[ar0]            = acc00[r];
        gb[ar0 + 16]       = acc01[r];
        gb[ar0 + 16 * 32]  = acc10[r];
        gb[ar0 + 16 * 33]  = acc11[r];
    }
}

// --- K3: S2 = sum wgt*(sum over KOUT partials)^2; last block writes loss ---
__global__ __launch_bounds__(256) void k_reduce_final(
    const float* __restrict__ gp, const float* __restrict__ svec,
    float* __restrict__ s2, int* __restrict__ ticket,
    float* __restrict__ out)
{
    __shared__ f4 accs[8][32];
    __shared__ float pw[4];
    __shared__ int lastFlag;
    const int t = threadIdx.x;
    const int cl = t & 31, q = t >> 5;               // 32 cells/block, 8 plane-groups
    const int c = blockIdx.x * 32 + cl;              // f4 cell, 34816 total
    const f4* g4 = (const f4*)gp;
    f4 sA = {0.f,0.f,0.f,0.f}, sB = {0.f,0.f,0.f,0.f};
    sA += g4[(size_t)(q * 4 + 0) * PLANE_F4 + c];
    sB += g4[(size_t)(q * 4 + 1) * PLANE_F4 + c];
    sA += g4[(size_t)(q * 4 + 2) * PLANE_F4 + c];
    sB += g4[(size_t)(q * 4 + 3) * PLANE_F4 + c];
    accs[q][cl] = sA + sB;
    __syncthreads();
    if (t < 32) {
        f4 tot = accs[0][t];
        #pragma unroll
        for (int qq = 1; qq < 8; ++qq) tot += accs[qq][t];
        int tt = c >> 8, ta = 0;                     // 256 f4 per tile plane
        while (tt >= 16 - ta) { tt -= 16 - ta; ++ta; }
        const float wgt = (tt == 0) ? 1.f : 2.f;     // diag vs off-diag tile
        float sq = wgt * (tot.x*tot.x + tot.y*tot.y + tot.z*tot.z + tot.w*tot.w);
        #pragma unroll
        for (int off = 1; off < 32; off <<= 1) sq += __shfl_xor(sq, off, 64);
        if (t == 0) {
            atomicAdd(s2, sq);
            __threadfence();
            lastFlag = (atomicAdd(ticket, 1) == RB - 1);
        }
    }
    __syncthreads();
    if (lastFlag) {                                  // block-uniform
        __threadfence();
        const float v0 = svec[t], v1 = svec[t + 256];
        float p = v0 * v0 + v1 * v1;
        #pragma unroll
        for (int off = 1; off < 64; off <<= 1) p += __shfl_xor(p, off, 64);
        if ((t & 63) == 0) pw[t >> 6] = p;
        __syncthreads();
        if (t == 0) {
            const float s1 = pw[0] + pw[1] + pw[2] + pw[3];
            const float S2 = atomicAdd(s2, 0.f);     // read accumulated total
            const double NN = 67108864.0;            // 8192^2
            out[0] = (float)((NN - 2.0 * (double)s1 + (double)S2) / NN);
        }
    }
}

extern "C" void kernel_launch(void* const* d_in, const int* in_sizes, int n_in,
                              void* d_out, int out_size, void* d_ws, size_t ws_size,
                              hipStream_t stream)
{
    const float* reps = (const float*)d_in[0];
    // d_in[1] (labels) is mathematically irrelevant for margin = 1.0.
    char* ws = (char*)d_ws;
    unsigned short* xt   = (unsigned short*)(ws + OFF_XT);
    float*          invn = (float*)(ws + OFF_INV);
    float*          svec = (float*)(ws + OFF_S);
    float*          s2   = (float*)(ws + OFF_S2);
    int*            tick = (int*)(ws + OFF_TK);
    float*          gp   = (float*)(ws + OFF_GP);

    k_norms<<<2048, 256, 0, stream>>>(reps, invn, svec);
    k_norm_transpose<<<dim3(8, 128), 256, 0, stream>>>(reps, invn, xt, svec);
    k_gram<<<NT32 * KOUT, 64, 0, stream>>>(xt, gp);
    k_reduce_final<<<RB, 256, 0, stream>>>(gp, svec, s2, tick, (float*)d_out);
}

// Round 6
// 91.404 us; speedup vs baseline: 1.3704x; 1.3704x over previous
//
#include <hip/hip_runtime.h>

// N = 8192 rows, D = 512 features.
// loss = mean((1-cos)^2) over all pairs (margin=1 makes labels irrelevant:
//        max(1-cos,0)^2 == (1-cos)^2 since cos <= 1).
// N^2*loss = N^2 - 2*||s||^2 + ||Xn^T Xn||_F^2,  s_a = sum_i xn[i][a].
// G = Xn^T Xn is 512x512 symmetric -> 136 upper-triangle 32x32 tiles,
// off-diagonal tiles weighted 2 in the Frobenius sum.
//
// xt is stored FRAGMENT-MAJOR: 1 KiB block per (g = feature-rowgroup of 16,
// c = sample-kchunk of 32); within a block, lane l holds 16 B for
// (row = l&15, k-slice = l>>4) — exactly the mfma_f32_16x16x32_bf16 A/B
// fragment. Gram loads are then contiguous 1 KiB per wave (zero overfetch).

typedef __attribute__((ext_vector_type(8))) short  s8;      // 8 bf16 payload
typedef __attribute__((ext_vector_type(8))) __bf16 bf8;     // mfma operand
typedef __attribute__((ext_vector_type(4))) float  f4;
typedef __attribute__((ext_vector_type(4))) unsigned short u4v;

#define NT32 136                 // 16*17/2 upper-triangle 32x32 tiles
#define KOUT 16                  // K splits
#define KCW  512                 // 8192 / KOUT (= 16 kchunks of 32)
#define GSTRIDE (256 * 512)      // ushorts per g-group (256 chunks * 512)

// ws layout (bytes)
#define OFF_XT  0u                               // bf16 xt[32g][256c][64l][8] = 8 MiB
#define OFF_INV (8u * 1024u * 1024u)             // f32 inv[8192]
#define OFF_S   (OFF_INV + 8192u * 4u)           // f32 svec[512]
#define OFF_S2  (OFF_S + 512u * 4u)              // f32 s2[1]
#define OFF_TK  (OFF_S2 + 4u)                    // int ticket[1]
#define OFF_GP  (OFF_S2 + 64u)                   // f32 gp[KOUT][NT32][1024] = 8.9 MiB

__device__ __forceinline__ unsigned short f2bf(float f) {
    union { float f; unsigned u; } v; v.f = f;
    unsigned r = v.u + 0x7FFFu + ((v.u >> 16) & 1u);   // RNE
    return (unsigned short)(r >> 16);
}

// --- K1a: per-row inv-norms (one wave/row) + zero svec/s2/ticket from blk 0 ---
__global__ __launch_bounds__(256) void k_norms(
    const float* __restrict__ reps, float* __restrict__ inv,
    float* __restrict__ zbuf /* svec[512] + s2 + ticket contiguous */)
{
    const int t = threadIdx.x, lane = t & 63, w = t >> 6;
    if (blockIdx.x == 0) {
        for (int z = t; z < 514; z += 256) zbuf[z] = 0.f;
    }
    const int row = blockIdx.x * 4 + w;
    const float4 x0 = *(const float4*)(reps + (size_t)row * 512 + lane * 4);
    const float4 x1 = *(const float4*)(reps + (size_t)row * 512 + 256 + lane * 4);
    float ss = x0.x*x0.x + x0.y*x0.y + x0.z*x0.z + x0.w*x0.w
             + x1.x*x1.x + x1.y*x1.y + x1.z*x1.z + x1.w*x1.w;
    #pragma unroll
    for (int off = 1; off < 64; off <<= 1) ss += __shfl_xor(ss, off, 64);
    if (lane == 0) inv[row] = 1.0f / fmaxf(sqrtf(ss), 1e-8f);
}

// --- K1b: normalize + bf16 + transpose into fragment-major xt + s-vector ---
__global__ __launch_bounds__(256) void k_norm_transpose(
    const float* __restrict__ reps, const float* __restrict__ inv,
    unsigned short* __restrict__ xt, float* __restrict__ svec)
{
    __shared__ unsigned short tile[64][72];     // +8 pad (round-1 counters: 0 conflicts)
    __shared__ float sred[4][64];
    const int t = threadIdx.x, lane = t & 63, w = t >> 6;
    const int a0 = blockIdx.x * 64, i0 = blockIdx.y * 64;
    const int colg = t & 15;                    // col group: cols colg*4..+3
    const int ig0  = t >> 4;                    // 0..15

    float4 sa = {0.f, 0.f, 0.f, 0.f};
    #pragma unroll
    for (int j = 0; j < 4; ++j) {
        const int il = ig0 + j * 16;
        const float iv = inv[i0 + il];
        const float4 x = *(const float4*)(reps + (size_t)(i0 + il) * 512 + a0 + colg * 4);
        const float4 xn = {x.x * iv, x.y * iv, x.z * iv, x.w * iv};
        sa.x += xn.x; sa.y += xn.y; sa.z += xn.z; sa.w += xn.w;
        ushort4 p;
        p.x = f2bf(xn.x); p.y = f2bf(xn.y); p.z = f2bf(xn.z); p.w = f2bf(xn.w);
        *(ushort4*)&tile[il][colg * 4] = p;
    }
    __syncthreads();

    // phase 2: register 4x4 sub-block transpose -> fragment-major 8B writes.
    // o_j = xn[i0+ig*4 .. +3][a0+ag*4+j]; dest block (g, c), lane = ks*16+rl,
    // half ke4: g = a>>4, rl = a&15, c = k>>5, ks = bits1..2 of ig, ke4 = ig&1.
    {
        const int ig = t & 15, ag = t >> 4;
        u4v rows[4];
        #pragma unroll
        for (int r = 0; r < 4; ++r)
            rows[r] = *(const u4v*)&tile[ig * 4 + r][ag * 4];
        const int gbase = a0 >> 4;
        const int c     = (i0 >> 5) + (ig >> 3);
        const int ks    = (ig >> 1) & 3;
        const int ke4   = ig & 1;
        #pragma unroll
        for (int j = 0; j < 4; ++j) {
            const int al = ag * 4 + j;          // a-local 0..63
            const int g  = gbase + (al >> 4);
            const int rl = al & 15;
            ushort4 o;
            o.x = (unsigned short)rows[0][j];
            o.y = (unsigned short)rows[1][j];
            o.z = (unsigned short)rows[2][j];
            o.w = (unsigned short)rows[3][j];
            *(ushort4*)(xt + ((((size_t)g * 256 + c) << 9)
                              + (ks * 16 + rl) * 8 + ke4 * 4)) = o;
        }
    }

    // s-vector: reduce over 16 i-groups (in-wave via shfl, cross-wave via LDS)
    sa.x += __shfl_xor(sa.x, 16, 64); sa.x += __shfl_xor(sa.x, 32, 64);
    sa.y += __shfl_xor(sa.y, 16, 64); sa.y += __shfl_xor(sa.y, 32, 64);
    sa.z += __shfl_xor(sa.z, 16, 64); sa.z += __shfl_xor(sa.z, 32, 64);
    sa.w += __shfl_xor(sa.w, 16, 64); sa.w += __shfl_xor(sa.w, 32, 64);
    if (lane < 16) {
        sred[w][lane * 4 + 0] = sa.x; sred[w][lane * 4 + 1] = sa.y;
        sred[w][lane * 4 + 2] = sa.z; sred[w][lane * 4 + 3] = sa.w;
    }
    __syncthreads();
    if (t < 64) {
        const float v = sred[0][t] + sred[1][t] + sred[2][t] + sred[3][t];
        atomicAdd(&svec[a0 + t], v);
    }
}

// --- K2: partial Gram, 32x32 upper-tri tiles; 1 wave = 1 tile x K-chunk.
//     Fragment-major xt: each operand load = contiguous 1 KiB per wave. ---
__global__ __launch_bounds__(64) void k_gram(
    const unsigned short* __restrict__ xt, float* __restrict__ gp)
{
    const int lane = threadIdx.x;
    const int l15 = lane & 15, l4 = lane >> 4;
    int tt = blockIdx.x, ta = 0;
    while (tt >= 16 - ta) { tt -= 16 - ta; ++ta; }
    const int tb = ta + tt;
    const int c0 = blockIdx.y * (KCW / 32);      // 16 kchunks per block
    const unsigned short* A0 = xt + (((size_t)(ta * 2) * 256 + c0) << 9) + lane * 8;
    const unsigned short* B0 = xt + (((size_t)(tb * 2) * 256 + c0) << 9) + lane * 8;

    f4 acc00 = {0.f,0.f,0.f,0.f}, acc01 = {0.f,0.f,0.f,0.f};
    f4 acc10 = {0.f,0.f,0.f,0.f}, acc11 = {0.f,0.f,0.f,0.f};

    if (ta != tb) {
        for (int cc = 0; cc < 16; ++cc) {
            const s8 av0 = *(const s8*)(A0 + cc * 512);
            const s8 av1 = *(const s8*)(A0 + GSTRIDE + cc * 512);
            const s8 bv0 = *(const s8*)(B0 + cc * 512);
            const s8 bv1 = *(const s8*)(B0 + GSTRIDE + cc * 512);
            acc00 = __builtin_amdgcn_mfma_f32_16x16x32_bf16(
                __builtin_bit_cast(bf8, av0), __builtin_bit_cast(bf8, bv0), acc00, 0, 0, 0);
            acc01 = __builtin_amdgcn_mfma_f32_16x16x32_bf16(
                __builtin_bit_cast(bf8, av0), __builtin_bit_cast(bf8, bv1), acc01, 0, 0, 0);
            acc10 = __builtin_amdgcn_mfma_f32_16x16x32_bf16(
                __builtin_bit_cast(bf8, av1), __builtin_bit_cast(bf8, bv0), acc10, 0, 0, 0);
            acc11 = __builtin_amdgcn_mfma_f32_16x16x32_bf16(
                __builtin_bit_cast(bf8, av1), __builtin_bit_cast(bf8, bv1), acc11, 0, 0, 0);
        }
    } else {
        for (int cc = 0; cc < 16; ++cc) {
            const s8 av0 = *(const s8*)(A0 + cc * 512);
            const s8 av1 = *(const s8*)(A0 + GSTRIDE + cc * 512);
            acc00 = __builtin_amdgcn_mfma_f32_16x16x32_bf16(
                __builtin_bit_cast(bf8, av0), __builtin_bit_cast(bf8, av0), acc00, 0, 0, 0);
            acc01 = __builtin_amdgcn_mfma_f32_16x16x32_bf16(
                __builtin_bit_cast(bf8, av0), __builtin_bit_cast(bf8, av1), acc01, 0, 0, 0);
            acc10 = __builtin_amdgcn_mfma_f32_16x16x32_bf16(
                __builtin_bit_cast(bf8, av1), __builtin_bit_cast(bf8, av0), acc10, 0, 0, 0);
            acc11 = __builtin_amdgcn_mfma_f32_16x16x32_bf16(
                __builtin_bit_cast(bf8, av1), __builtin_bit_cast(bf8, av1), acc11, 0, 0, 0);
        }
    }

    float* gb = gp + ((size_t)blockIdx.y * NT32 + blockIdx.x) * 1024;
    #pragma unroll
    for (int r = 0; r < 4; ++r) {
        const int ar0 = (l4 * 4 + r) * 32 + l15;     // C/D: row=(l>>4)*4+r, col=l&15
        gb[ar0]           = acc00[r];
        gb[ar0 + 16]      = acc01[r];
        gb[ar0 + 16 * 32] = acc10[r];
        gb[ar0 + 16 * 33] = acc11[r];
    }
}

// --- K3: S2 = sum wgt*(sum over KOUT partials)^2; last block writes loss ---
__global__ __launch_bounds__(256) void k_reduce_final(
    const float* __restrict__ gp, const float* __restrict__ svec,
    float* __restrict__ s2, int* __restrict__ ticket,
    float* __restrict__ out)
{
    __shared__ float part[4];
    __shared__ int lastFlag;
    const int t = threadIdx.x;
    const int c = blockIdx.x * 256 + t;              // f4 cell, 34816 total
    const f4* g4 = (const f4*)gp;
    f4 s = {0.f, 0.f, 0.f, 0.f};
    #pragma unroll
    for (int p = 0; p < KOUT; ++p) s += g4[(size_t)p * (NT32 * 256) + c];
    int tt = c >> 8, ta = 0;                         // 256 f4 per tile plane
    while (tt >= 16 - ta) { tt -= 16 - ta; ++ta; }
    const float wgt = (tt == 0) ? 1.f : 2.f;         // diag vs off-diag tile
    float sq = wgt * (s.x * s.x + s.y * s.y + s.z * s.z + s.w * s.w);
    #pragma unroll
    for (int off = 1; off < 64; off <<= 1) sq += __shfl_xor(sq, off, 64);
    if ((t & 63) == 0) part[t >> 6] = sq;
    __syncthreads();
    if (t == 0) {
        atomicAdd(s2, part[0] + part[1] + part[2] + part[3]);
        __threadfence();
        lastFlag = (atomicAdd(ticket, 1) == (int)gridDim.x - 1);
    }
    __syncthreads();
    if (lastFlag) {                                  // block-uniform
        __threadfence();
        const float v0 = svec[t], v1 = svec[t + 256];
        float p = v0 * v0 + v1 * v1;
        #pragma unroll
        for (int off = 1; off < 64; off <<= 1) p += __shfl_xor(p, off, 64);
        if ((t & 63) == 0) part[t >> 6] = p;
        __syncthreads();
        if (t == 0) {
            const float s1 = part[0] + part[1] + part[2] + part[3];
            const float S2 = atomicAdd(s2, 0.f);     // read accumulated total
            const double NN = 67108864.0;            // 8192^2
            out[0] = (float)((NN - 2.0 * (double)s1 + (double)S2) / NN);
        }
    }
}

extern "C" void kernel_launch(void* const* d_in, const int* in_sizes, int n_in,
                              void* d_out, int out_size, void* d_ws, size_t ws_size,
                              hipStream_t stream)
{
    const float* reps = (const float*)d_in[0];
    // d_in[1] (labels) is mathematically irrelevant for margin = 1.0.
    char* ws = (char*)d_ws;
    unsigned short* xt   = (unsigned short*)(ws + OFF_XT);
    float*          invn = (float*)(ws + OFF_INV);
    float*          svec = (float*)(ws + OFF_S);
    float*          s2   = (float*)(ws + OFF_S2);
    int*            tick = (int*)(ws + OFF_TK);
    float*          gp   = (float*)(ws + OFF_GP);

    k_norms<<<2048, 256, 0, stream>>>(reps, invn, svec);
    k_norm_transpose<<<dim3(8, 128), 256, 0, stream>>>(reps, invn, xt, svec);
    k_gram<<<dim3(NT32, KOUT), 64, 0, stream>>>(xt, gp);
    k_reduce_final<<<NT32, 256, 0, stream>>>(gp, svec, s2, tick, (float*)d_out);
}

// Round 7
// 87.332 us; speedup vs baseline: 1.4343x; 1.0466x over previous
//
#include <hip/hip_runtime.h>

// N = 8192 rows, D = 512 features.
// loss = mean((1-cos)^2) over all pairs (margin=1 makes labels irrelevant:
//        max(1-cos,0)^2 == (1-cos)^2 since cos <= 1).
// N^2*loss = N^2 - 2*||s||^2 + ||Xn^T Xn||_F^2,  s_a = sum_i xn[i][a].
// G = Xn^T Xn is 512x512 symmetric -> 136 upper-triangle 32x32 tiles,
// off-diagonal tiles weighted 2 in the Frobenius sum.
//
// xt is FRAGMENT-MAJOR: 1 KiB block per (g = feature-group of 16,
// c = sample-chunk of 32); lane l holds 16 B for (feature-row = l&15,
// k-slice = l>>4) — exactly the mfma_f32_16x16x32_bf16 A/B fragment.
// Gram loads are contiguous 1 KiB per wave (zero overfetch).

typedef __attribute__((ext_vector_type(8))) short  s8;      // 8 bf16 payload
typedef __attribute__((ext_vector_type(8))) __bf16 bf8;     // mfma operand
typedef __attribute__((ext_vector_type(4))) float  f4;

#define NT32 136                 // 16*17/2 upper-triangle 32x32 tiles
#define KOUT 16                  // K splits
#define KCW  512                 // 8192 / KOUT (= 16 kchunks of 32)
#define GSTRIDE (256 * 512)      // ushorts per g-group (256 chunks * 512)

// ws layout (bytes)
#define OFF_XT  0u                               // bf16 xt[32g][256c][64l][8] = 8 MiB
#define OFF_S2  (8u * 1024u * 1024u)             // f32 s2[1]
#define OFF_TK  (OFF_S2 + 4u)                    // int ticket[1]
#define OFF_PRT (OFF_S2 + 64u)                   // f32 parts[256][512] = 512 KiB
#define OFF_GP  (OFF_PRT + 256u * 512u * 4u)     // f32 gp[KOUT][NT32][1024] = 8.9 MiB

__device__ __forceinline__ unsigned short f2bf(float f) {
    union { float f; unsigned u; } v; v.f = f;
    unsigned r = v.u + 0x7FFFu + ((v.u >> 16) & 1u);   // RNE
    return (unsigned short)(r >> 16);
}
__device__ __forceinline__ float bf2f(unsigned short h) {
    union { unsigned u; float f; } v; v.u = ((unsigned)h) << 16;
    return v.f;
}

// --- K1: fused norms + normalize + fragment-major transpose + svec parts.
//     Block b owns rows [32b, 32b+32) = sample-chunk c = b. 256 thr. ---
__global__ __launch_bounds__(256) void k_prep(
    const float* __restrict__ reps, unsigned short* __restrict__ xt,
    float* __restrict__ parts, float* __restrict__ s2, int* __restrict__ ticket)
{
    __shared__ unsigned short tile[32][528];    // 512 + 16 pad ushorts
    const int t = threadIdx.x, lane = t & 63, wv = t >> 6;
    const int b = blockIdx.x;
    if (b == 0 && t == 0) { *s2 = 0.f; *ticket = 0; }

    // phase A: load 32 rows, octet-reduce sumsq, normalize, pack to LDS
    const int row = wv * 8 + (lane >> 3);       // local row 0..31
    const int co  = (lane & 7) * 4;             // col base (f32)
    const float* rp = reps + (size_t)(b * 32 + row) * 512 + co;
    float4 v[16];
    float ss = 0.f;
    #pragma unroll
    for (int q = 0; q < 16; ++q) {
        v[q] = *(const float4*)(rp + 32 * q);
        ss += v[q].x*v[q].x + v[q].y*v[q].y + v[q].z*v[q].z + v[q].w*v[q].w;
    }
    ss += __shfl_xor(ss, 1, 64);
    ss += __shfl_xor(ss, 2, 64);
    ss += __shfl_xor(ss, 4, 64);                // all 8 octet lanes have row sumsq
    const float inv = 1.0f / fmaxf(sqrtf(ss), 1e-8f);
    #pragma unroll
    for (int q = 0; q < 16; ++q) {
        ushort4 p;
        p.x = f2bf(v[q].x * inv); p.y = f2bf(v[q].y * inv);
        p.z = f2bf(v[q].z * inv); p.w = f2bf(v[q].w * inv);
        *(ushort4*)&tile[row][co + 32 * q] = p;
    }
    __syncthreads();

    // phase B: fragment-major output. Slot (g, l): l = ks*16+rl holds
    // bf16 xn[b*32 + ks*8 + j][g*16 + rl], j=0..7.
    {
        const int rl = lane & 15, ks = lane >> 4;
        #pragma unroll
        for (int gg = 0; gg < 8; ++gg) {
            const int g = wv * 8 + gg;
            const int a = g * 16 + rl;
            ushort4 o0, o1;
            o0.x = tile[ks*8+0][a]; o0.y = tile[ks*8+1][a];
            o0.z = tile[ks*8+2][a]; o0.w = tile[ks*8+3][a];
            o1.x = tile[ks*8+4][a]; o1.y = tile[ks*8+5][a];
            o1.z = tile[ks*8+6][a]; o1.w = tile[ks*8+7][a];
            unsigned short* dst = xt + ((size_t)g << 17) + ((size_t)b << 9) + lane * 8;
            *(ushort4*)(dst)     = o0;
            *(ushort4*)(dst + 4) = o1;
        }
    }

    // phase C: svec partials for this 32-row chunk (features t and t+256)
    {
        float sA = 0.f, sB = 0.f;
        #pragma unroll
        for (int r = 0; r < 32; ++r) {
            sA += bf2f(tile[r][t]);
            sB += bf2f(tile[r][t + 256]);
        }
        parts[(size_t)b * 512 + t]       = sA;
        parts[(size_t)b * 512 + t + 256] = sB;
    }
}

// --- K2: partial Gram, 32x32 upper-tri tiles; 1 wave = 1 tile x K-chunk.
//     Fragment-major xt: each operand load = contiguous 1 KiB per wave.
//     (unchanged from round 6 — proven) ---
__global__ __launch_bounds__(64) void k_gram(
    const unsigned short* __restrict__ xt, float* __restrict__ gp)
{
    const int lane = threadIdx.x;
    const int l15 = lane & 15, l4 = lane >> 4;
    int tt = blockIdx.x, ta = 0;
    while (tt >= 16 - ta) { tt -= 16 - ta; ++ta; }
    const int tb = ta + tt;
    const int c0 = blockIdx.y * (KCW / 32);      // 16 kchunks per block
    const unsigned short* A0 = xt + (((size_t)(ta * 2) * 256 + c0) << 9) + lane * 8;
    const unsigned short* B0 = xt + (((size_t)(tb * 2) * 256 + c0) << 9) + lane * 8;

    f4 acc00 = {0.f,0.f,0.f,0.f}, acc01 = {0.f,0.f,0.f,0.f};
    f4 acc10 = {0.f,0.f,0.f,0.f}, acc11 = {0.f,0.f,0.f,0.f};

    if (ta != tb) {
        for (int cc = 0; cc < 16; ++cc) {
            const s8 av0 = *(const s8*)(A0 + cc * 512);
            const s8 av1 = *(const s8*)(A0 + GSTRIDE + cc * 512);
            const s8 bv0 = *(const s8*)(B0 + cc * 512);
            const s8 bv1 = *(const s8*)(B0 + GSTRIDE + cc * 512);
            acc00 = __builtin_amdgcn_mfma_f32_16x16x32_bf16(
                __builtin_bit_cast(bf8, av0), __builtin_bit_cast(bf8, bv0), acc00, 0, 0, 0);
            acc01 = __builtin_amdgcn_mfma_f32_16x16x32_bf16(
                __builtin_bit_cast(bf8, av0), __builtin_bit_cast(bf8, bv1), acc01, 0, 0, 0);
            acc10 = __builtin_amdgcn_mfma_f32_16x16x32_bf16(
                __builtin_bit_cast(bf8, av1), __builtin_bit_cast(bf8, bv0), acc10, 0, 0, 0);
            acc11 = __builtin_amdgcn_mfma_f32_16x16x32_bf16(
                __builtin_bit_cast(bf8, av1), __builtin_bit_cast(bf8, bv1), acc11, 0, 0, 0);
        }
    } else {
        for (int cc = 0; cc < 16; ++cc) {
            const s8 av0 = *(const s8*)(A0 + cc * 512);
            const s8 av1 = *(const s8*)(A0 + GSTRIDE + cc * 512);
            acc00 = __builtin_amdgcn_mfma_f32_16x16x32_bf16(
                __builtin_bit_cast(bf8, av0), __builtin_bit_cast(bf8, av0), acc00, 0, 0, 0);
            acc01 = __builtin_amdgcn_mfma_f32_16x16x32_bf16(
                __builtin_bit_cast(bf8, av0), __builtin_bit_cast(bf8, av1), acc01, 0, 0, 0);
            acc10 = __builtin_amdgcn_mfma_f32_16x16x32_bf16(
                __builtin_bit_cast(bf8, av1), __builtin_bit_cast(bf8, av0), acc10, 0, 0, 0);
            acc11 = __builtin_amdgcn_mfma_f32_16x16x32_bf16(
                __builtin_bit_cast(bf8, av1), __builtin_bit_cast(bf8, av1), acc11, 0, 0, 0);
        }
    }

    float* gb = gp + ((size_t)blockIdx.y * NT32 + blockIdx.x) * 1024;
    #pragma unroll
    for (int r = 0; r < 4; ++r) {
        const int ar0 = (l4 * 4 + r) * 32 + l15;     // C/D: row=(l>>4)*4+r, col=l&15
        gb[ar0]           = acc00[r];
        gb[ar0 + 16]      = acc01[r];
        gb[ar0 + 16 * 32] = acc10[r];
        gb[ar0 + 16 * 33] = acc11[r];
    }
}

// --- K3: s2 += wgt*(sum_K gp)^2 over gp cells  AND  -2*s_a^2 over features;
//     last-ticket block writes loss = (N^2 + s2)/N^2. ---
__global__ __launch_bounds__(256) void k_reduce_final(
    const float* __restrict__ gp, const float* __restrict__ parts,
    float* __restrict__ s2, int* __restrict__ ticket, float* __restrict__ out)
{
    __shared__ float part[4], svp[4];
    __shared__ int lastFlag;
    const int t = threadIdx.x, lane = t & 63, wv = t >> 6;
    const int c = blockIdx.x * 256 + t;              // f4 cell, 34816 total
    const f4* g4 = (const f4*)gp;
    f4 s = {0.f, 0.f, 0.f, 0.f};
    #pragma unroll
    for (int p = 0; p < KOUT; ++p) s += g4[(size_t)p * (NT32 * 256) + c];
    int tt = c >> 8, ta = 0;                         // 256 f4 per tile plane
    while (tt >= 16 - ta) { tt -= 16 - ta; ++ta; }
    const float wgt = (tt == 0) ? 1.f : 2.f;         // diag vs off-diag tile
    float sq = wgt * (s.x * s.x + s.y * s.y + s.z * s.z + s.w * s.w);
    #pragma unroll
    for (int off = 1; off < 64; off <<= 1) sq += __shfl_xor(sq, off, 64);
    if (lane == 0) part[wv] = sq;

    // s1 slice: blocks 0..127, wave wv owns feature a = blk*4 + wv
    float sv = 0.f;
    if (blockIdx.x < 128) {
        const int a = blockIdx.x * 4 + wv;
        #pragma unroll
        for (int pb = 0; pb < 4; ++pb) sv += parts[(size_t)(pb * 64 + lane) * 512 + a];
        #pragma unroll
        for (int off = 1; off < 64; off <<= 1) sv += __shfl_xor(sv, off, 64);
    }
    if (lane == 0) svp[wv] = sv;
    __syncthreads();
    if (t == 0) {
        const float tot = part[0] + part[1] + part[2] + part[3]
            - 2.f * (svp[0]*svp[0] + svp[1]*svp[1] + svp[2]*svp[2] + svp[3]*svp[3]);
        atomicAdd(s2, tot);
        __threadfence();
        lastFlag = (atomicAdd(ticket, 1) == (int)gridDim.x - 1);
    }
    __syncthreads();
    if (lastFlag) {                                  // block-uniform
        __threadfence();
        if (t == 0) {
            const float S = atomicAdd(s2, 0.f);      // full S2 - 2*s1
            const double NN = 67108864.0;            // 8192^2
            out[0] = (float)((NN + (double)S) / NN);
        }
    }
}

extern "C" void kernel_launch(void* const* d_in, const int* in_sizes, int n_in,
                              void* d_out, int out_size, void* d_ws, size_t ws_size,
                              hipStream_t stream)
{
    const float* reps = (const float*)d_in[0];
    // d_in[1] (labels) is mathematically irrelevant for margin = 1.0.
    char* ws = (char*)d_ws;
    unsigned short* xt   = (unsigned short*)(ws + OFF_XT);
    float*          s2   = (float*)(ws + OFF_S2);
    int*            tick = (int*)(ws + OFF_TK);
    float*          prt  = (float*)(ws + OFF_PRT);
    float*          gp   = (float*)(ws + OFF_GP);

    k_prep<<<256, 256, 0, stream>>>(reps, xt, prt, s2, tick);
    k_gram<<<dim3(NT32, KOUT), 64, 0, stream>>>(xt, gp);
    k_reduce_final<<<NT32, 256, 0, stream>>>(gp, prt, s2, tick, (float*)d_out);
}